// Round 3
// baseline (2793.438 us; speedup 1.0000x reference)
//
#include <hip/hip_runtime.h>

// Persistent 2-layer LSTM, T=512, B=64, H=512. fp32 in/out, bf16 MFMA.
// Round-1 architecture (proven passing): 8 domains = {l0,l1} x {4 batch
// groups of 16 rows}, 32 blocks/domain, all sync via L3 (sc0 sc1), per-block
// flags. NO grid barriers, NO XCD assumptions (round-2 hang post-mortem).
// This round:
//  (1) weights+biases PINNED in VGPRs via identity-asm. Round-1 VGPR=104 <
//      128 needed for breg => compiler re-loaded 64KB of weights per block
//      per STEP (asm "memory" clobbers legalize it). Pinning makes them
//      opaque asm results.
//  (2) flag preloading: flag loads issued under covered windows (x-MFMA
//      phase / store-drain), checked via register tie; poll loop only on
//      miss. Saves ~1 L3 RT/step in the common case.
//  (3) L1 wait split: producer check -> issue h0 load -> own-domain poll
//      overlapping h0 flight -> h1 load (poll hidden under load latency).
//  (4) out/final stores moved after flag publish (off the drain path).

#define T_SEQ 512

typedef short s16x8 __attribute__((ext_vector_type(8)));
typedef int   i32x4 __attribute__((ext_vector_type(4)));
typedef float f32x4 __attribute__((ext_vector_type(4)));

__device__ __forceinline__ short f2bf(float f) {
    unsigned u = __builtin_bit_cast(unsigned, f);
    unsigned r = (u + 0x7fffu + ((u >> 16) & 1u)) >> 16;   // RNE
    return (short)r;
}
__device__ __forceinline__ float sigf(float x) { return 1.0f / (1.0f + __expf(-x)); }
__device__ __forceinline__ float tanhff(float x) { return 2.0f * sigf(2.0f * x) - 1.0f; }

// ---- setup: cast x (fp32) -> bf16 ----
__global__ __launch_bounds__(256) void xcast_kernel(const float* __restrict__ x,
                                                    short* __restrict__ xb) {
    int i = (blockIdx.x * 256 + threadIdx.x) * 8;
    float4 a = *(const float4*)(x + i);
    float4 b = *(const float4*)(x + i + 4);
    s16x8 v;
    v[0]=f2bf(a.x); v[1]=f2bf(a.y); v[2]=f2bf(a.z); v[3]=f2bf(a.w);
    v[4]=f2bf(b.x); v[5]=f2bf(b.y); v[6]=f2bf(b.z); v[7]=f2bf(b.w);
    *(s16x8*)(xb + i) = v;
}

// ---- setup: pack weights [l][bb][w][g][kk0..7][lane][8] bf16 ----
__global__ __launch_bounds__(256) void wpack_kernel(const float* __restrict__ Wxh,
                                                    const float* __restrict__ Whh,
                                                    short* __restrict__ wp) {
    int fg = blockIdx.x * 256 + threadIdx.x;        // [0, 524288)
    int lane = fg & 63;
    int kk   = (fg >> 6)  & 7;
    int g    = (fg >> 9)  & 3;
    int w    = (fg >> 11) & 3;
    int bb   = (fg >> 13) & 31;
    int l    = (fg >> 18) & 1;
    int ksrc = w * 128 + (kk & 3) * 32 + (lane >> 4) * 8;
    int jp   = g * 512 + bb * 16 + (lane & 15);
    const float* src = (kk < 4) ? (Wxh + ((size_t)(l * 2048 + jp) * 512 + ksrc))
                                : (Whh + ((size_t)(l * 2048 + jp) * 512 + ksrc));
    float4 a = *(const float4*)src;
    float4 b = *(const float4*)(src + 4);
    s16x8 v;
    v[0]=f2bf(a.x); v[1]=f2bf(a.y); v[2]=f2bf(a.z); v[3]=f2bf(a.w);
    v[4]=f2bf(b.x); v[5]=f2bf(b.y); v[6]=f2bf(b.z); v[7]=f2bf(b.w);
    *(s16x8*)(wp + (size_t)fg * 8) = v;
}

// ---- L3-coherent 4-frag load (with wait) ----
__device__ __forceinline__ void load4_l3(i32x4 af[4], const short* base) {
    asm volatile(
        "global_load_dwordx4 %0, %4, off sc0 sc1\n\t"
        "global_load_dwordx4 %1, %4, off offset:64 sc0 sc1\n\t"
        "global_load_dwordx4 %2, %4, off offset:128 sc0 sc1\n\t"
        "global_load_dwordx4 %3, %4, off offset:192 sc0 sc1\n\t"
        "s_waitcnt vmcnt(0)"
        : "=&v"(af[0]), "=&v"(af[1]), "=&v"(af[2]), "=&v"(af[3])
        : "v"(base) : "memory");
}
// ---- L3-coherent 4-frag load, ISSUE ONLY (no wait) ----
__device__ __forceinline__ void load4_l3_issue(i32x4 af[4], const short* base) {
    asm volatile(
        "global_load_dwordx4 %0, %4, off sc0 sc1\n\t"
        "global_load_dwordx4 %1, %4, off offset:64 sc0 sc1\n\t"
        "global_load_dwordx4 %2, %4, off offset:128 sc0 sc1\n\t"
        "global_load_dwordx4 %3, %4, off offset:192 sc0 sc1"
        : "=&v"(af[0]), "=&v"(af[1]), "=&v"(af[2]), "=&v"(af[3])
        : "v"(base) : "memory");
}
// tie: wait + create reg dependency so MFMA can't be hoisted above (rule #18)
__device__ __forceinline__ void tie4(i32x4 af[4]) {
    asm volatile("s_waitcnt vmcnt(0)"
                 : "+v"(af[0]), "+v"(af[1]), "+v"(af[2]), "+v"(af[3]) :: "memory");
}

// ---- flag preload: issue 2 flag loads, no wait ----
__device__ __forceinline__ void flag_issue(int* v0, int* v1,
                                           const unsigned* fa, const unsigned* fb,
                                           int lane) {
    const unsigned* pa = fa + (lane & 31);
    const unsigned* pb = fb + (lane & 31);
    asm volatile("global_load_dword %0, %2, off sc0 sc1\n\t"
                 "global_load_dword %1, %3, off sc0 sc1"
                 : "=&v"(*v0), "=&v"(*v1) : "v"(pa), "v"(pb) : "memory");
}
// tie for preloaded flags; vmcnt(0): nothing else outstanding at call site
__device__ __forceinline__ void tie2_0(int* a, int* b) {
    asm volatile("s_waitcnt vmcnt(0)" : "+v"(*a), "+v"(*b) :: "memory");
}
// vmcnt(1): one NEWER vmem op (the out store) may stay in flight; the two
// flag loads are the oldest outstanding ops at the call site.
__device__ __forceinline__ void tie2_1(int* a, int* b) {
    asm volatile("s_waitcnt vmcnt(1)" : "+v"(*a), "+v"(*b) :: "memory");
}

// ---- fallback polls ----
__device__ __forceinline__ void pollf(const unsigned* f, int thr, int lane) {
    if (thr <= 0) return;
    const unsigned* p = f + (lane & 31);
    int v;
    do {
        asm volatile("global_load_dword %0, %1, off sc0 sc1\n\t"
                     "s_waitcnt vmcnt(0)"
                     : "=&v"(v) : "v"(p) : "memory");
    } while (v < thr);
}
// merged poll, one load per lane: lanes 0-31 cover fa, 32-63 cover fb
__device__ __forceinline__ void pollf2(const unsigned* fa, int ta,
                                       const unsigned* fb, int tb, int lane) {
    const unsigned* p = (lane < 32) ? (fa + lane) : (fb + (lane - 32));
    int thr = (lane < 32) ? ta : tb;
    int v;
    do {
        asm volatile("global_load_dword %0, %1, off sc0 sc1\n\t"
                     "s_waitcnt vmcnt(0)"
                     : "=&v"(v) : "v"(p) : "memory");
    } while (v < thr);
}

// ---- coherent scalar stores ----
__device__ __forceinline__ void sth_l3(short* p, int bits) {
    asm volatile("global_store_short %0, %1, off sc0 sc1" :: "v"(p), "v"(bits) : "memory");
}
__device__ __forceinline__ void stf_l3(unsigned* p, int v) {
    asm volatile("global_store_dword %0, %1, off sc0 sc1" :: "v"(p), "v"(v) : "memory");
}

#define DRAIN() asm volatile("s_waitcnt vmcnt(0)" ::: "memory")

#define MFMA16(FR, WS)                                                        \
    _Pragma("unroll") for (int kk = 0; kk < 4; ++kk)                          \
    _Pragma("unroll") for (int g4 = 0; g4 < 4; ++g4)                          \
        acc[g4] = __builtin_amdgcn_mfma_f32_16x16x32_bf16(                    \
            __builtin_bit_cast(s16x8, FR[kk]), breg[g4][(WS) + kk],           \
            acc[g4], 0, 0, 0);

#define REDUCE_EPILOGUE()                                                     \
    _Pragma("unroll") for (int g4 = 0; g4 < 4; ++g4)                          \
        _Pragma("unroll") for (int q = 0; q < 4; ++q)                         \
            red[(wv * 4 + g4) * 288                                           \
                + ((lane >> 4) * 4 + q) * 18 + (lane & 15)] = acc[g4][q];     \
    __syncthreads();                                                          \
    float cg[4];                                                              \
    _Pragma("unroll") for (int g4 = 0; g4 < 4; ++g4) {                        \
        float s = bsum[g4];                                                   \
        _Pragma("unroll") for (int w = 0; w < 4; ++w)                         \
            s += red[(w * 4 + g4) * 288 + em * 18 + ec];                      \
        cg[g4] = s;                                                           \
    }                                                                         \
    float cn = sigf(cg[1]) * creg + sigf(cg[0]) * tanhff(cg[2]);              \
    hv = sigf(cg[3]) * tanhff(cn);                                            \
    creg = cn;

__global__ __launch_bounds__(256, 1) void lstm_persist(
    const short* __restrict__ xb,    // [T][64][512] bf16
    const short* __restrict__ wp,    // packed weights
    short* __restrict__ h0r,         // [8][64][512] bf16 ring (slot s = h0[s-1])
    short* __restrict__ h1r,         // [8][64][512] bf16 ring
    const float* __restrict__ bxh,   // [2][2048]
    const float* __restrict__ bhh,   // [2][2048]
    float* __restrict__ out,         // T*B*H | hT[2,B,H] | cT[2,B,H]
    unsigned* flags) {               // [2 layers][4 groups][32 blocks]

    const int l    = blockIdx.x >> 7;        // layer
    const int g    = (blockIdx.x >> 5) & 3;  // batch group (rows g*16..g*16+15)
    const int bb   = blockIdx.x & 31;        // col block (16 h-cols)
    const int tid  = threadIdx.x;
    const int wv   = tid >> 6;
    const int lane = tid & 63;

    __shared__ float red[16 * 288];  // [wv*4+g4][krow:16, stride 18]

    // ---- weights into registers, then PIN as opaque asm results so the
    // "memory" clobbers in the loop cannot legalize per-step re-loads ----
    s16x8 breg[4][8];
    {
        const short* wb = wp + (size_t)((l * 32 + bb) * 4 + wv) * 16384 + lane * 8;
        #pragma unroll
        for (int g4 = 0; g4 < 4; ++g4)
            #pragma unroll
            for (int kk = 0; kk < 8; ++kk)
                breg[g4][kk] = *(const s16x8*)(wb + (g4 * 8 + kk) * 512);
    }
    #pragma unroll
    for (int g4 = 0; g4 < 4; ++g4)
        asm volatile("" : "+v"(breg[g4][0]), "+v"(breg[g4][1]), "+v"(breg[g4][2]),
                          "+v"(breg[g4][3]), "+v"(breg[g4][4]), "+v"(breg[g4][5]),
                          "+v"(breg[g4][6]), "+v"(breg[g4][7]));

    // ---- epilogue constants: thread owns 1 cell (row em, col ej) ----
    const int em = tid >> 4;        // 0..15 (row within group)
    const int ec = tid & 15;        // 0..15 (col within block)
    const int ej = bb * 16 + ec;
    float bsum[4];
    #pragma unroll
    for (int g4 = 0; g4 < 4; ++g4)
        bsum[g4] = bxh[l * 2048 + g4 * 512 + ej] + bhh[l * 2048 + g4 * 512 + ej];
    asm volatile("" : "+v"(bsum[0]), "+v"(bsum[1]), "+v"(bsum[2]), "+v"(bsum[3]));

    float creg = 0.f, hv = 0.f;

    const int arow  = lane & 15;
    const int acol  = wv * 128 + (lane >> 4) * 8;   // + kk*32 (as 64 B asm offsets)
    const int aboff = (g * 16 + arow) * 512 + acol;

    const unsigned* fown = flags + (l * 4 + g) * 32;
    const unsigned* foth = flags + ((1 - l) * 4 + g) * 32;
    unsigned* myflag = (unsigned*)fown + bb;

    if (l == 0) {
        for (int t = 0; t < T_SEQ; ++t) {
            // issue flag preloads; latency hides under x loads + MFMA phase
            int pv0 = 0, pv1 = 0;
            flag_issue(&pv0, &pv1, fown, foth, lane);

            f32x4 acc[4];
            #pragma unroll
            for (int g4 = 0; g4 < 4; ++g4) acc[g4] = (f32x4){0.f,0.f,0.f,0.f};

            // input half = x[t]: no dependency, normal cached loads
            const short* ab = xb + (size_t)t * 32768 + aboff;
            s16x8 ax[4];
            #pragma unroll
            for (int kk = 0; kk < 4; ++kk)
                ax[kk] = *(const s16x8*)(ab + kk * 32);
            MFMA16(ax, 0)

            // check preloaded flags (own >= t, l1 backpressure >= t-7)
            tie2_0(&pv0, &pv1);
            if (pv0 < t || pv1 < t - 7) pollf2(fown, t, foth, t - 7, lane);

            i32x4 af[4];
            load4_l3(af, h0r + (size_t)(t & 7) * 32768 + aboff);
            MFMA16(af, 4)

            REDUCE_EPILOGUE()

            // h ring store + drain + publish
            sth_l3(h0r + (size_t)((t + 1) & 7) * 32768 + (g * 16 + em) * 512 + ej,
                   (int)(unsigned short)f2bf(hv));
            DRAIN();
            __syncthreads();
            if (tid == 0) stf_l3(myflag, t + 1);
        }
    } else {
        int pw0 = 0, pw1 = 0;     // preloaded fown(=FL1), foth(=FL0)
        for (int t = 0; t < T_SEQ; ++t) {
            tie2_1(&pw0, &pw1);
            // producer h0[t] ready? (FL0 >= t+1; L0 runs ahead -> usually yes)
            if (pw1 < t + 1) pollf(foth, t + 1, lane);
            i32x4 ag[4];
            load4_l3_issue(ag, h0r + (size_t)((t + 1) & 7) * 32768 + aboff);
            // own-domain h1[t-1] (poll overlaps the ag flight)
            if (pw0 < t) pollf(fown, t, lane);
            i32x4 af[4];
            load4_l3(af, h1r + (size_t)(t & 7) * 32768 + aboff);
            tie4(ag);

            f32x4 acc[4];
            #pragma unroll
            for (int g4 = 0; g4 < 4; ++g4) acc[g4] = (f32x4){0.f,0.f,0.f,0.f};
            MFMA16(af, 4)           // recurrent half (h1)
            MFMA16(ag, 0)           // input half (h0)

            REDUCE_EPILOGUE()

            sth_l3(h1r + (size_t)((t + 1) & 7) * 32768 + (g * 16 + em) * 512 + ej,
                   (int)(unsigned short)f2bf(hv));
            DRAIN();
            __syncthreads();
            if (tid == 0) stf_l3(myflag, t + 1);
            // preload next step's flags (covered by the publish window);
            // out store issued AFTER so tie2_1's vmcnt(1) leaves only it
            flag_issue(&pw0, &pw1, fown, foth, lane);
            out[(size_t)t * 32768 + (size_t)(g * 16 + em) * 512 + ej] = hv;
        }
    }

    // final h/c state
    size_t base = (size_t)T_SEQ * 32768;
    out[base + (size_t)(l * 64 + g * 16 + em) * 512 + ej] = hv;
    out[base + 65536 + (size_t)(l * 64 + g * 16 + em) * 512 + ej] = creg;
}

extern "C" void kernel_launch(void* const* d_in, const int* in_sizes, int n_in,
                              void* d_out, int out_size, void* d_ws, size_t ws_size,
                              hipStream_t stream) {
    const float* x   = (const float*)d_in[0];
    const float* Wxh = (const float*)d_in[1];
    const float* Whh = (const float*)d_in[2];
    const float* bxh = (const float*)d_in[3];
    const float* bhh = (const float*)d_in[4];
    float* out = (float*)d_out;

    char* ws = (char*)d_ws;
    short*    xb    = (short*)(ws);                     // 33,554,432 B
    short*    wpk   = (short*)(ws + 33554432);          //  8,388,608 B
    short*    h0r   = (short*)(ws + 41943040);          //    524,288 B
    short*    h1r   = (short*)(ws + 42467328);          //    524,288 B
    unsigned* flags = (unsigned*)(ws + 42991616);       //      1,024 B

    // zero rings + flags (ws re-poisoned 0xAA before every timed launch)
    hipMemsetAsync(ws + 41943040, 0, 1049600, stream);

    xcast_kernel<<<dim3(8192), dim3(256), 0, stream>>>(x, xb);
    wpack_kernel<<<dim3(2048), dim3(256), 0, stream>>>(Wxh, Whh, wpk);

    lstm_persist<<<dim3(256), dim3(256), 0, stream>>>(xb, wpk, h0r, h1r,
                                                      bxh, bhh, out, flags);
}